// Round 1
// baseline (727.919 us; speedup 1.0000x reference)
//
#include <hip/hip_runtime.h>
#include <hip/hip_bf16.h>

#define N_TOK 4096
#define H_DIM 2048
#define I_DIM 1408
#define E_NUM 8
#define CAP   1280

typedef __hip_bfloat16 bf16;
typedef __bf16 bf16x8 __attribute__((ext_vector_type(8)));
typedef float f32x4 __attribute__((ext_vector_type(4)));

__device__ inline void gld_lds16(const void* g, void* l) {
    __builtin_amdgcn_global_load_lds((const __attribute__((address_space(1))) void*)g,
                                     (__attribute__((address_space(3))) void*)l,
                                     16, 0, 0);
}

// ---------------- fp32 -> bf16 conversion (vectorized) ----------------
__global__ void cvt4(const float* __restrict__ s, unsigned short* __restrict__ d, long n) {
    long i = ((long)blockIdx.x * blockDim.x + threadIdx.x) * 4;
    if (i >= n) return;
    float4 v = *(const float4*)(s + i);
    union { unsigned short u[4]; ushort2 h[2]; } o;
    bf16 b0 = __float2bfloat16(v.x);
    bf16 b1 = __float2bfloat16(v.y);
    bf16 b2 = __float2bfloat16(v.z);
    bf16 b3 = __float2bfloat16(v.w);
    o.u[0] = *(unsigned short*)&b0;
    o.u[1] = *(unsigned short*)&b1;
    o.u[2] = *(unsigned short*)&b2;
    o.u[3] = *(unsigned short*)&b3;
    *(ushort2*)(d + i)     = o.h[0];
    *(ushort2*)(d + i + 2) = o.h[1];
}

// ---------------- router: logits -> softmax -> top2 ----------------
__global__ void router_k(const float* __restrict__ x, const float* __restrict__ Wr,
                         float* __restrict__ top_val, int* __restrict__ top_idx) {
    int tok  = (blockIdx.x * blockDim.x + threadIdx.x) >> 6;
    int lane = threadIdx.x & 63;
    if (tok >= N_TOK) return;
    const float* xr = x + (size_t)tok * H_DIM;
    float acc[E_NUM];
#pragma unroll
    for (int e = 0; e < E_NUM; e++) acc[e] = 0.f;
    for (int h = lane; h < H_DIM; h += 64) {
        float xv = xr[h];
#pragma unroll
        for (int e = 0; e < E_NUM; e++) acc[e] += xv * Wr[e * H_DIM + h];
    }
#pragma unroll
    for (int e = 0; e < E_NUM; e++) {
#pragma unroll
        for (int off = 32; off > 0; off >>= 1) acc[e] += __shfl_xor(acc[e], off, 64);
    }
    if (lane == 0) {
        float mx = acc[0];
#pragma unroll
        for (int e = 1; e < E_NUM; e++) mx = fmaxf(mx, acc[e]);
        float p[E_NUM], s = 0.f;
#pragma unroll
        for (int e = 0; e < E_NUM; e++) { p[e] = __expf(acc[e] - mx); s += p[e]; }
        float inv = 1.f / s;
#pragma unroll
        for (int e = 0; e < E_NUM; e++) p[e] *= inv;
        int i0 = 0;
#pragma unroll
        for (int e = 1; e < E_NUM; e++) if (p[e] > p[i0]) i0 = e;
        int i1 = -1;
#pragma unroll
        for (int e = 0; e < E_NUM; e++) {
            if (e == i0) continue;
            if (i1 < 0 || p[e] > p[i1]) i1 = e;
        }
        top_idx[tok * 2]     = i0;
        top_idx[tok * 2 + 1] = i1;
        top_val[tok * 2]     = p[i0];
        top_val[tok * 2 + 1] = p[i1];
    }
}

// ---------------- capacity assignment (single block, deterministic) ----------------
__global__ void assign_k(const int* __restrict__ top_idx, const float* __restrict__ top_val,
                         int* __restrict__ toklist, float* __restrict__ wlist,
                         int* __restrict__ counts) {
    const int T = 256;
    const int CH = (2 * N_TOK) / T; // 32
    int t = threadIdx.x;
    // init lists to sentinel (row N_TOK = zero row), weight 0
    for (int i = t; i < E_NUM * CAP; i += T) { toklist[i] = N_TOK; wlist[i] = 0.f; }
    __shared__ int cnt[T][E_NUM];
    int local[E_NUM];
#pragma unroll
    for (int e = 0; e < E_NUM; e++) local[e] = 0;
    for (int q = 0; q < CH; q++) {
        int j = t * CH + q;
        int slot = j >> 12;      // j / 4096
        int tok  = j & 4095;
        int e = top_idx[tok * 2 + slot];
        local[e]++;
    }
#pragma unroll
    for (int e = 0; e < E_NUM; e++) cnt[t][e] = local[e];
    __syncthreads();
    if (t < E_NUM) {
        int run = 0;
        for (int i = 0; i < T; i++) { int c = cnt[i][t]; cnt[i][t] = run; run += c; }
        counts[t] = run < CAP ? run : CAP;
    }
    __syncthreads();
    int run[E_NUM];
#pragma unroll
    for (int e = 0; e < E_NUM; e++) run[e] = cnt[t][e];
    for (int q = 0; q < CH; q++) {
        int j = t * CH + q;
        int slot = j >> 12;
        int tok  = j & 4095;
        int e = top_idx[tok * 2 + slot];
        int rank = ++run[e];           // inclusive rank in flat order
        if (rank <= CAP) {
            toklist[e * CAP + rank - 1] = tok;
            wlist[e * CAP + rank - 1]   = top_val[tok * 2 + slot];
        }
    }
}

// ---------------- per-expert GEMM (A row-major gathered, B=W row-major [n][k]) ----
// MODE 0: g = silu(X @ Wg^T)          -> gbuf   (bf16)
// MODE 1: h = gbuf * (X @ Wu^T)       -> hbuf   (bf16)
// MODE 2: out[tok] += w * (h @ Wd^T)  -> atomicAdd fp32
template <int MODE>
__global__ __launch_bounds__(256)
void expert_gemm(const unsigned short* __restrict__ A, const unsigned short* __restrict__ W,
                 unsigned short* __restrict__ gbuf, unsigned short* __restrict__ hbuf,
                 float* __restrict__ out,
                 const int* __restrict__ toklist, const float* __restrict__ wlist,
                 const int* __restrict__ counts, int Ndim, int K) {
    const int e  = blockIdx.z;
    const int m0 = blockIdx.y * 128;
    const int n0 = blockIdx.x * 128;
    if (m0 >= counts[e]) return;   // whole tile is padding

    __shared__ unsigned short As[128 * 32];
    __shared__ unsigned short Bs[128 * 32];

    const int t  = threadIdx.x;
    const int r0 = t >> 2;          // staging row 0..63
    const int c8 = (t & 3) * 8;     // staging col group

    const unsigned short *aP0, *aP1;
    if (MODE < 2) {
        int tok0 = toklist[e * CAP + m0 + r0];
        int tok1 = toklist[e * CAP + m0 + r0 + 64];
        aP0 = A + (size_t)tok0 * K + c8;
        aP1 = A + (size_t)tok1 * K + c8;
    } else {
        aP0 = A + ((size_t)e * CAP + m0 + r0) * (size_t)K + c8;
        aP1 = aP0 + (size_t)64 * K;
    }
    const unsigned short* bP0 = W + (size_t)e * Ndim * K + (size_t)(n0 + r0) * K + c8;
    const unsigned short* bP1 = bP0 + (size_t)64 * K;

    unsigned short* ldsA0 = As + t * 8;          // == base + lane*16B, wave-uniform base
    unsigned short* ldsA1 = ldsA0 + 64 * 32;
    unsigned short* ldsB0 = Bs + t * 8;
    unsigned short* ldsB1 = ldsB0 + 64 * 32;

    const int lane = t & 63;
    const int wave = t >> 6;
    const int wm   = (wave & 1) * 64;
    const int wn   = (wave >> 1) * 64;
    const int l15  = lane & 15;
    const int quad = lane >> 4;

    f32x4 acc[4][4];
#pragma unroll
    for (int i = 0; i < 4; i++)
#pragma unroll
        for (int j = 0; j < 4; j++) acc[i][j] = (f32x4){0.f, 0.f, 0.f, 0.f};

    for (int k = 0; k < K; k += 32) {
        gld_lds16(aP0, ldsA0);
        gld_lds16(aP1, ldsA1);
        gld_lds16(bP0, ldsB0);
        gld_lds16(bP1, ldsB1);
        aP0 += 32; aP1 += 32; bP0 += 32; bP1 += 32;
        __syncthreads();
        bf16x8 af[4], bfr[4];
#pragma unroll
        for (int i = 0; i < 4; i++)
            af[i] = *(const bf16x8*)(As + (wm + i * 16 + l15) * 32 + quad * 8);
#pragma unroll
        for (int j = 0; j < 4; j++)
            bfr[j] = *(const bf16x8*)(Bs + (wn + j * 16 + l15) * 32 + quad * 8);
#pragma unroll
        for (int i = 0; i < 4; i++)
#pragma unroll
            for (int j = 0; j < 4; j++)
                acc[i][j] = __builtin_amdgcn_mfma_f32_16x16x32_bf16(af[i], bfr[j], acc[i][j], 0, 0, 0);
        __syncthreads();
    }

    // epilogue: C/D layout col = lane&15, row = quad*4 + reg
    if (MODE == 0) {
#pragma unroll
        for (int i = 0; i < 4; i++) {
            int mb = m0 + wm + i * 16 + quad * 4;
#pragma unroll
            for (int r = 0; r < 4; r++) {
                size_t rowoff = ((size_t)e * CAP + mb + r) * I_DIM;
#pragma unroll
                for (int j = 0; j < 4; j++) {
                    int n = n0 + wn + j * 16 + l15;
                    float v = acc[i][j][r];
                    float sg = v / (1.f + __expf(-v));   // silu
                    bf16 b = __float2bfloat16(sg);
                    gbuf[rowoff + n] = *(unsigned short*)&b;
                }
            }
        }
    } else if (MODE == 1) {
#pragma unroll
        for (int i = 0; i < 4; i++) {
            int mb = m0 + wm + i * 16 + quad * 4;
#pragma unroll
            for (int r = 0; r < 4; r++) {
                size_t rowoff = ((size_t)e * CAP + mb + r) * I_DIM;
#pragma unroll
                for (int j = 0; j < 4; j++) {
                    int n = n0 + wn + j * 16 + l15;
                    unsigned short gu = gbuf[rowoff + n];
                    float sg = __bfloat162float(*(bf16*)&gu);
                    bf16 b = __float2bfloat16(sg * acc[i][j][r]);
                    hbuf[rowoff + n] = *(unsigned short*)&b;
                }
            }
        }
    } else {
#pragma unroll
        for (int i = 0; i < 4; i++) {
            int mb = m0 + wm + i * 16 + quad * 4;
#pragma unroll
            for (int r = 0; r < 4; r++) {
                int tok = toklist[e * CAP + mb + r];
                if (tok < N_TOK) {
                    float wgt = wlist[e * CAP + mb + r];
                    float* orow = out + (size_t)tok * H_DIM + n0 + wn + l15;
#pragma unroll
                    for (int j = 0; j < 4; j++)
                        atomicAdd(orow + j * 16, wgt * acc[i][j][r]);
                }
            }
        }
    }
}

extern "C" void kernel_launch(void* const* d_in, const int* in_sizes, int n_in,
                              void* d_out, int out_size, void* d_ws, size_t ws_size,
                              hipStream_t stream) {
    const float* x  = (const float*)d_in[0];
    const float* Wr = (const float*)d_in[1];
    const float* Wg = (const float*)d_in[2];
    const float* Wu = (const float*)d_in[3];
    const float* Wd = (const float*)d_in[4];
    float* out = (float*)d_out;

    char* p = (char*)d_ws;
    auto alloc = [&](size_t bytes) { char* r = p; p += (bytes + 255) & ~(size_t)255; return r; };
    unsigned short* xb   = (unsigned short*)alloc((size_t)(N_TOK + 1) * H_DIM * 2);
    unsigned short* Wgb  = (unsigned short*)alloc((size_t)E_NUM * I_DIM * H_DIM * 2);
    unsigned short* Wub  = (unsigned short*)alloc((size_t)E_NUM * I_DIM * H_DIM * 2);
    unsigned short* Wdb  = (unsigned short*)alloc((size_t)E_NUM * H_DIM * I_DIM * 2);
    unsigned short* gbuf = (unsigned short*)alloc((size_t)E_NUM * CAP * I_DIM * 2);
    unsigned short* hbuf = (unsigned short*)alloc((size_t)E_NUM * CAP * I_DIM * 2);
    float* top_val = (float*)alloc((size_t)N_TOK * 2 * 4);
    int*   top_idx = (int*)alloc((size_t)N_TOK * 2 * 4);
    int*   toklist = (int*)alloc((size_t)E_NUM * CAP * 4);
    float* wlist   = (float*)alloc((size_t)E_NUM * CAP * 4);
    int*   counts  = (int*)alloc((size_t)E_NUM * 4);

    hipMemsetAsync(out, 0, (size_t)N_TOK * H_DIM * 4, stream);
    hipMemsetAsync(xb + (size_t)N_TOK * H_DIM, 0, H_DIM * 2, stream); // zero row for padding

    long nx = (long)N_TOK * H_DIM;
    long nw = (long)E_NUM * I_DIM * H_DIM;
    cvt4<<<dim3((unsigned)((nx / 4 + 255) / 256)), dim3(256), 0, stream>>>(x, xb, nx);
    cvt4<<<dim3((unsigned)((nw / 4 + 255) / 256)), dim3(256), 0, stream>>>(Wg, Wgb, nw);
    cvt4<<<dim3((unsigned)((nw / 4 + 255) / 256)), dim3(256), 0, stream>>>(Wu, Wub, nw);
    cvt4<<<dim3((unsigned)((nw / 4 + 255) / 256)), dim3(256), 0, stream>>>(Wd, Wdb, nw);

    router_k<<<dim3(N_TOK / 4), dim3(256), 0, stream>>>(x, Wr, top_val, top_idx);
    assign_k<<<dim3(1), dim3(256), 0, stream>>>(top_idx, top_val, toklist, wlist, counts);

    dim3 g1(I_DIM / 128, CAP / 128, E_NUM);
    expert_gemm<0><<<g1, dim3(256), 0, stream>>>(xb, Wgb, gbuf, nullptr, nullptr, toklist, wlist, counts, I_DIM, H_DIM);
    expert_gemm<1><<<g1, dim3(256), 0, stream>>>(xb, Wub, gbuf, hbuf, nullptr, toklist, wlist, counts, I_DIM, H_DIM);
    dim3 g2(H_DIM / 128, CAP / 128, E_NUM);
    expert_gemm<2><<<g2, dim3(256), 0, stream>>>(hbuf, Wdb, nullptr, nullptr, out, toklist, wlist, counts, H_DIM, I_DIM);
}